// Round 9
// baseline (330.642 us; speedup 1.0000x reference)
//
#include <hip/hip_runtime.h>
#include <math.h>

// B=64, A=64, MULS=((64,0),(32,1),(16,2)) -> DIM_IN=240, NB=32, H=128, MOUT=112
#define H_ 128
#define NB_ 32

#define INV_STEP 3.1f
#define HALF_PI 1.57079632679489662f
#define INV_SQRT_NB 0.17677669529663689f
#define INV_SQRT_H 0.08838834764831845f
#define NORM0 0.125f
#define NORM1 0.10206207261596575f
#define NORM2 0.11180339887498948f
#define S3 1.7320508075688772f
#define S5 2.23606797749979f
#define S15 3.872983346207417f
// log2-domain softplus constants
#define SSP_C1 7.2134752044448170f    // 5*log2(e)
#define SSP_C2 0.1386294361119891f    // ln2/5

typedef __attribute__((ext_vector_type(8))) _Float16 half8;
typedef __attribute__((ext_vector_type(4))) float f32x4;

// v_exp_f32 computes 2^x; v_log_f32 computes log2(x)
__device__ __forceinline__ float ssp_f(float x) {
    // (softplus(5x)-ln2)/5 computed in log2 domain
    float u = SSP_C1 * x;
    float p = __builtin_amdgcn_exp2f(-fabsf(u));
    float t = fmaxf(u, 0.f) + __builtin_amdgcn_logf(1.f + p);
    return fmaf(t, SSP_C2, -SSP_C2);
}
__device__ __forceinline__ float sp_f(float x) {
    float u = SSP_C1 * x;
    float p = __builtin_amdgcn_exp2f(-fabsf(u));
    float t = fmaxf(u, 0.f) + __builtin_amdgcn_logf(1.f + p);
    return t * SSP_C2;
}

// ---------------------------------------------------------------------------
// w2half: W2 (fp32 row-major) -> fp16 MFMA-B-fragment order in ws.
// ---------------------------------------------------------------------------
__global__ void w2half(const float* __restrict__ W2, _Float16* __restrict__ w2f) {
    const int e0 = (blockIdx.x * 256 + threadIdx.x) * 4;
    #pragma unroll
    for (int t = 0; t < 4; ++t) {
        const int pos = e0 + t;
        const int j = pos & 7, lane = (pos >> 3) & 63, fn = pos >> 9;
        const int kt = fn >> 3, nt = fn & 7;
        const int k = kt * 32 + (lane >> 4) * 8 + j;
        const int n = nt * 16 + (lane & 15);
        w2f[pos] = (_Float16)W2[k * 128 + n];
    }
}

// V-slot helper: computes one fp16 B-fragment (8 h values for one (b,kt,qd,cm))
template <int K>
__device__ __forceinline__ void vslot(const float* __restrict__ W3,
                                      const float* __restrict__ rr,
                                      int colbase, int repBase, int repStride,
                                      int repOff, int h0, float nrm,
                                      _Float16* __restrict__ dst) {
    float accj[8] = {0.f, 0.f, 0.f, 0.f, 0.f, 0.f, 0.f, 0.f};
    for (int u0 = 0; u0 < K; u0 += 16) {
        float rv[16];
        #pragma unroll
        for (int t = 0; t < 16; ++t)
            rv[t] = rr[repBase + (u0 + t) * repStride + repOff];
        #pragma unroll
        for (int j = 0; j < 8; ++j) {
            const float* w3r = W3 + (size_t)(h0 + j) * 112 + colbase + u0;
            float4 w0 = *reinterpret_cast<const float4*>(w3r);
            float4 w1 = *reinterpret_cast<const float4*>(w3r + 4);
            float4 w2 = *reinterpret_cast<const float4*>(w3r + 8);
            float4 w3v = *reinterpret_cast<const float4*>(w3r + 12);
            const float* wp0 = reinterpret_cast<const float*>(&w0);
            const float* wp1 = reinterpret_cast<const float*>(&w1);
            const float* wp2 = reinterpret_cast<const float*>(&w2);
            const float* wp3 = reinterpret_cast<const float*>(&w3v);
            float a = accj[j];
            #pragma unroll
            for (int c = 0; c < 4; ++c) a = fmaf(wp0[c], rv[c], a);
            #pragma unroll
            for (int c = 0; c < 4; ++c) a = fmaf(wp1[c], rv[4 + c], a);
            #pragma unroll
            for (int c = 0; c < 4; ++c) a = fmaf(wp2[c], rv[8 + c], a);
            #pragma unroll
            for (int c = 0; c < 4; ++c) a = fmaf(wp3[c], rv[12 + c], a);
            accj[j] = a;
        }
    }
    half8 o;
    #pragma unroll
    for (int j = 0; j < 8; ++j) o[j] = (_Float16)(accj[j] * nrm);
    *reinterpret_cast<half8*>(dst) = o;
}

// ---------------------------------------------------------------------------
// pair5: grid (16, 64): bg owns 4 b's; 4 blocks/CU (LDS ~39 KB).
// Startup: stage geom/rep; V -> fp16 B-frags in LDS, one frag per thread-slot
//          (conflict-free b128 writes, uniform K per wave).
// Main (2 passes x 2 b): layer1 in fp16 A-frag regs (W1 global/L1) ->
//          fp16 MFMA layer2 (W2 frags global/L1) -> ssp -> fp16 LDS transpose
//          (stride 136) -> fp16 MFMA combine vs V frags -> G-weight ->
//          16-lane shuffle reduce.
// Output: partial[z][bg][a]; counter-based finalize by last of 16 blocks.
// ---------------------------------------------------------------------------
__global__ __launch_bounds__(256, 4)
void pair5(const float* __restrict__ rep, const float* __restrict__ geom,
           const float* __restrict__ mask, const float* __restrict__ W1,
           const float* __restrict__ W3, const _Float16* __restrict__ w2f,
           float* __restrict__ partial, unsigned* __restrict__ counter,
           float* __restrict__ out) {
    const int bg = blockIdx.x;           // b in [4bg, 4bg+4)
    const int z  = blockIdx.y;
    const int tid = threadIdx.x;
    const int wv = tid >> 6, lane = tid & 63;
    const int m = lane & 15, quad = lane >> 4;

    __shared__ __align__(16) _Float16 sVf[8192];       // 16384 B  [b4][kt][lane][j]
    __shared__ __align__(16) _Float16 sH2w[4][16 * 136]; // 17408 B (sRep alias)
    __shared__ float sPosA[192];
    __shared__ float sPosB[12];
    __shared__ __align__(16) float sYw[4][2][16][8];   // 4096 B
    __shared__ unsigned sLastFlag;

    float* sRep = reinterpret_cast<float*>(&sH2w[0][0]);  // 960 floats, dead later

    // ---- stage geom + rep ----
    if (tid < 192) sPosA[tid] = geom[z * 192 + tid];
    else if (tid < 204) sPosB[tid - 192] = geom[((size_t)z * 64 + bg * 4) * 3 + (tid - 192)];
    if (tid < 240)
        reinterpret_cast<float4*>(sRep)[tid] =
            reinterpret_cast<const float4*>(rep + ((size_t)z * 64 + bg * 4) * 240)[tid];
    __syncthreads();

    // ---- V compute: one fragment per slot, class per wave ----
    const float nI = INV_SQRT_H;
    if (wv == 0) {
        // 64 slots, cm=0, K=64
        const int r = lane;
        const int b = r >> 4, kt = (r >> 2) & 3, qd = r & 3;
        vslot<64>(W3, sRep + b * 240, 0, 0, 1, 0, kt * 32 + qd * 8, NORM0 * nI,
                  sVf + (b * 4 + kt) * 512 + (qd * 16 + 0) * 8);
    } else if (wv == 1) {
        // 192 slots, cm=1..3, K=32
        #pragma unroll
        for (int s = 0; s < 3; ++s) {
            const int idx = lane + 64 * s;
            const int mm = idx % 3, r = idx / 3;
            const int b = r >> 4, kt = (r >> 2) & 3, qd = r & 3;
            vslot<32>(W3, sRep + b * 240, 64, 64, 3, mm, kt * 32 + qd * 8, NORM1 * nI,
                      sVf + (b * 4 + kt) * 512 + (qd * 16 + 1 + mm) * 8);
        }
    } else if (wv == 2) {
        // 320 slots, cm=4..8, K=16
        #pragma unroll
        for (int s = 0; s < 5; ++s) {
            const int idx = lane + 64 * s;
            const int t5 = idx % 5, r = idx / 5;
            const int b = r >> 4, kt = (r >> 2) & 3, qd = r & 3;
            vslot<16>(W3, sRep + b * 240, 96, 160, 5, t5, kt * 32 + qd * 8, NORM2 * nI,
                      sVf + (b * 4 + kt) * 512 + (qd * 16 + 4 + t5) * 8);
        }
    } else {
        // 448 zero slots (n = 9..15)
        half8 zz = {};
        #pragma unroll
        for (int s = 0; s < 7; ++s) {
            const int idx = lane + 64 * s;
            const int t7 = idx % 7, r = idx / 7;
            const int b = r >> 4, kt = (r >> 2) & 3, qd = r & 3;
            *reinterpret_cast<half8*>(sVf + (b * 4 + kt) * 512 + (qd * 16 + 9 + t7) * 8) = zz;
        }
    }
    __syncthreads();   // sVf ready; sRep dead -> sH2w usable

    // ---- main loop: 2 passes x 2 b ----
    const int aLoc = wv * 16 + m;
    const float axw = sPosA[aLoc * 3 + 0];
    const float ayw = sPosA[aLoc * 3 + 1];
    const float azw = sPosA[aLoc * 3 + 2];
    _Float16* myH2 = &sH2w[wv][0];
    float outAcc[4] = {0.f, 0.f, 0.f, 0.f};

    for (int pass = 0; pass < 2; ++pass) {
        const float* w1p0[2];
        const float* w1p1[2];
        float c0v[2], c1v[2];

        #pragma unroll
        for (int p = 0; p < 2; ++p) {
            const int bl = pass * 2 + p;
            const float bx = sPosB[bl * 3 + 0];
            const float by = sPosB[bl * 3 + 1];
            const float bz = sPosB[bl * 3 + 2];
            const float dx = axw - bx, dy = ayw - by, dz = azw - bz;
            const float r2 = dx * dx + dy * dy + dz * dz;
            const float r = sqrtf(fmaxf(r2, 1e-12f));
            const float nzf = (r2 > 1e-10f) ? 1.0f : 0.0f;
            const float ir = 1.0f / r;
            const float x = dx * ir, y = dy * ir, zz = dz * ir;
            if (quad == 0) {
                float4 g0, g1;
                g0.x = S3 * x * nzf; g0.y = S3 * y * nzf; g0.z = S3 * zz * nzf;
                g0.w = S15 * x * y * nzf;
                g1.x = S15 * y * zz * nzf;
                g1.y = 0.5f * S5 * (3.0f * zz * zz - 1.0f) * nzf;
                g1.z = S15 * x * zz * nzf;
                g1.w = 0.5f * S15 * (x * x - y * y) * nzf;
                *reinterpret_cast<float4*>(&sYw[wv][p][m][0]) = g0;
                *reinterpret_cast<float4*>(&sYw[wv][p][m][4]) = g1;
            }
            const float u = r * INV_STEP;
            int i0 = (int)floorf(u);
            const float d0 = u - (float)i0;
            float c0 = (i0 >= 0 && i0 < NB_) ? __cosf(HALF_PI * d0) : 0.f;
            const int i1 = i0 + 1;
            const float d1 = d0 - 1.0f;
            float c1 = (i1 >= 0 && i1 < NB_ && d1 > -1.0f) ? __cosf(HALF_PI * d1) : 0.f;
            const int i0c = min(max(i0, 0), NB_ - 1);
            const int i1c = min(max(i1, 0), NB_ - 1);
            w1p0[p] = W1 + i0c * H_;
            w1p1[p] = W1 + i1c * H_;
            c0v[p] = c0 * INV_SQRT_NB;
            c1v[p] = c1 * INV_SQRT_NB;
        }

        f32x4 acc[2][8];
        #pragma unroll
        for (int p = 0; p < 2; ++p)
            #pragma unroll
            for (int nt = 0; nt < 8; ++nt) {
                acc[p][nt][0] = 0.f; acc[p][nt][1] = 0.f;
                acc[p][nt][2] = 0.f; acc[p][nt][3] = 0.f;
            }

        // ---- layer1 (fp16 A-frag regs, W1 via L1) + layer2 MFMA (W2 frags via L1) ----
        #pragma unroll
        for (int kt = 0; kt < 4; ++kt) {
            const int koff = kt * 32 + quad * 8;
            half8 ah[2];
            #pragma unroll
            for (int p = 0; p < 2; ++p) {
                float4 wa0 = *reinterpret_cast<const float4*>(w1p0[p] + koff);
                float4 wa1 = *reinterpret_cast<const float4*>(w1p0[p] + koff + 4);
                float4 wb0 = *reinterpret_cast<const float4*>(w1p1[p] + koff);
                float4 wb1 = *reinterpret_cast<const float4*>(w1p1[p] + koff + 4);
                const float* a0p = reinterpret_cast<const float*>(&wa0);
                const float* a1p = reinterpret_cast<const float*>(&wa1);
                const float* b0p = reinterpret_cast<const float*>(&wb0);
                const float* b1p = reinterpret_cast<const float*>(&wb1);
                #pragma unroll
                for (int j = 0; j < 8; ++j) {
                    float w0 = (j < 4) ? a0p[j] : a1p[j - 4];
                    float w1v = (j < 4) ? b0p[j] : b1p[j - 4];
                    ah[p][j] = (_Float16)ssp_f(fmaf(c0v[p], w0, c1v[p] * w1v));
                }
            }
            const _Float16* bhp = w2f + (size_t)(kt * 8) * 512 + (size_t)lane * 8;
            #pragma unroll
            for (int nt = 0; nt < 8; ++nt) {
                half8 bh = *reinterpret_cast<const half8*>(bhp + nt * 512);
                acc[0][nt] = __builtin_amdgcn_mfma_f32_16x16x32_f16(ah[0], bh, acc[0][nt], 0, 0, 0);
                acc[1][nt] = __builtin_amdgcn_mfma_f32_16x16x32_f16(ah[1], bh, acc[1][nt], 0, 0, 0);
            }
        }

        // ---- per-b epilogue ----
        #pragma unroll
        for (int p = 0; p < 2; ++p) {
            const int bl = pass * 2 + p;
            // ssp + fp16 transpose through wave-private LDS (stride 136)
            #pragma unroll
            for (int nt = 0; nt < 8; ++nt)
                #pragma unroll
                for (int reg = 0; reg < 4; ++reg)
                    myH2[(quad * 4 + reg) * 136 + nt * 16 + m] =
                        (_Float16)ssp_f(acc[p][nt][reg] * INV_SQRT_H);

            f32x4 T0 = {0.f, 0.f, 0.f, 0.f};
            f32x4 T1 = {0.f, 0.f, 0.f, 0.f};
            #pragma unroll
            for (int kt = 0; kt < 4; ++kt) {
                half8 ah2 = *reinterpret_cast<const half8*>(&myH2[m * 136 + kt * 32 + quad * 8]);
                half8 bv = *reinterpret_cast<const half8*>(&sVf[(bl * 4 + kt) * 512 + lane * 8]);
                if (kt & 1) T1 = __builtin_amdgcn_mfma_f32_16x16x32_f16(ah2, bv, T1, 0, 0, 0);
                else        T0 = __builtin_amdgcn_mfma_f32_16x16x32_f16(ah2, bv, T0, 0, 0, 0);
            }

            // G-weight (T C-layout: col=lane&15=cm, row=quad*4+reg) + 16-lane reduce
            const int comp = (m >= 1 && m <= 8) ? (m - 1) : 0;
            float ps[4];
            #pragma unroll
            for (int reg = 0; reg < 4; ++reg) {
                const int row = quad * 4 + reg;
                const float Tv = T0[reg] + T1[reg];
                const float yv = sYw[wv][p][row][comp];
                const float g = (m == 0) ? 1.0f : ((m <= 8) ? yv : 0.0f);
                ps[reg] = Tv * g;
            }
            #pragma unroll
            for (int off = 1; off < 16; off <<= 1)
                #pragma unroll
                for (int reg = 0; reg < 4; ++reg)
                    ps[reg] += __shfl_xor(ps[reg], off);
            #pragma unroll
            for (int reg = 0; reg < 4; ++reg) outAcc[reg] += ps[reg];
        }
    }

    // ---- write partials (agent scope) + completion-counter finalize ----
    if (m == 0) {
        float* pb = partial + ((size_t)(z * 16 + bg)) * 64 + wv * 16 + quad * 4;
        #pragma unroll
        for (int reg = 0; reg < 4; ++reg)
            __hip_atomic_store(&pb[reg], outAcc[reg], __ATOMIC_RELAXED,
                               __HIP_MEMORY_SCOPE_AGENT);
    }
    __threadfence();
    __syncthreads();
    if (tid == 0) {
        unsigned old = atomicAdd(&counter[z], 1u);
        sLastFlag = (old == 0xAAAAAAAAu + 15u) ? 1u : 0u;
    }
    __syncthreads();
    if (sLastFlag) {
        __threadfence();
        if (tid < 64) {
            const float mk = mask[z * 64 + tid];
            float s = mk;
            #pragma unroll
            for (int off = 32; off > 0; off >>= 1) s += __shfl_xor(s, off);
            const float inv = rsqrtf(s);
            float acc = 0.f;
            #pragma unroll
            for (int b2 = 0; b2 < 16; ++b2)
                acc += __hip_atomic_load(&partial[((size_t)(z * 16 + b2)) * 64 + tid],
                                         __ATOMIC_RELAXED, __HIP_MEMORY_SCOPE_AGENT);
            out[z * 64 + tid] = sp_f(acc * inv) * mk;
        }
    }
}

extern "C" void kernel_launch(void* const* d_in, const int* in_sizes, int n_in,
                              void* d_out, int out_size, void* d_ws, size_t ws_size,
                              hipStream_t stream) {
    const float* rep  = (const float*)d_in[0];
    const float* geom = (const float*)d_in[1];
    const float* mask = (const float*)d_in[2];
    const float* W1   = (const float*)d_in[3];
    const float* W2   = (const float*)d_in[4];
    const float* W3   = (const float*)d_in[5];
    float* out = (float*)d_out;

    _Float16* w2f = (_Float16*)d_ws;                          // 32768 B
    float* partial = (float*)((char*)d_ws + 32768);           // 64*16*64*4 = 262144 B
    unsigned* counter = (unsigned*)((char*)d_ws + 32768 + 262144);  // 64 uints (0xAA)

    w2half<<<16, 256, 0, stream>>>(W2, w2f);
    pair5<<<dim3(16, 64), 256, 0, stream>>>(rep, geom, mask, W1, W3, w2f,
                                            partial, counter, out);
}

// Round 10
// 296.499 us; speedup vs baseline: 1.1152x; 1.1152x over previous
//
#include <hip/hip_runtime.h>
#include <math.h>

// B=64, A=64, MULS=((64,0),(32,1),(16,2)) -> DIM_IN=240, NB=32, H=128, MOUT=112
#define H_ 128
#define NB_ 32

#define INV_STEP 3.1f
#define HALF_PI 1.57079632679489662f
#define INV_SQRT_NB 0.17677669529663689f
#define INV_SQRT_H 0.08838834764831845f
#define NORM0 0.125f
#define NORM1 0.10206207261596575f
#define NORM2 0.11180339887498948f
#define S3 1.7320508075688772f
#define S5 2.23606797749979f
#define S15 3.872983346207417f
// log2-domain softplus constants
#define SSP_C1 7.2134752044448170f    // 5*log2(e)
#define SSP_C2 0.1386294361119891f    // ln2/5

typedef __attribute__((ext_vector_type(8))) _Float16 half8;
typedef __attribute__((ext_vector_type(4))) float f32x4;

// v_exp_f32 computes 2^x; v_log_f32 computes log2(x)
__device__ __forceinline__ float ssp_f(float x) {
    float u = SSP_C1 * x;
    float p = __builtin_amdgcn_exp2f(-fabsf(u));
    float t = fmaxf(u, 0.f) + __builtin_amdgcn_logf(1.f + p);
    return fmaf(t, SSP_C2, -SSP_C2);
}
__device__ __forceinline__ float sp_f(float x) {
    float u = SSP_C1 * x;
    float p = __builtin_amdgcn_exp2f(-fabsf(u));
    float t = fmaxf(u, 0.f) + __builtin_amdgcn_logf(1.f + p);
    return t * SSP_C2;
}

// ---------------------------------------------------------------------------
// w2half: W2 (fp32 row-major) -> fp16 MFMA-B-fragment order in ws.
// ---------------------------------------------------------------------------
__global__ void w2half(const float* __restrict__ W2, _Float16* __restrict__ w2f) {
    const int e0 = (blockIdx.x * 256 + threadIdx.x) * 4;
    #pragma unroll
    for (int t = 0; t < 4; ++t) {
        const int pos = e0 + t;
        const int j = pos & 7, lane = (pos >> 3) & 63, fn = pos >> 9;
        const int kt = fn >> 3, nt = fn & 7;
        const int k = kt * 32 + (lane >> 4) * 8 + j;
        const int n = nt * 16 + (lane & 15);
        w2f[pos] = (_Float16)W2[k * 128 + n];
    }
}

// V-slot helper: computes one fp16 B-fragment (8 h values for one (b,kt,qd,cm))
template <int K>
__device__ __forceinline__ void vslot(const float* __restrict__ W3,
                                      const float* __restrict__ rr,
                                      int colbase, int repBase, int repStride,
                                      int repOff, int h0, float nrm,
                                      _Float16* __restrict__ dst) {
    float accj[8] = {0.f, 0.f, 0.f, 0.f, 0.f, 0.f, 0.f, 0.f};
    for (int u0 = 0; u0 < K; u0 += 16) {
        float rv[16];
        #pragma unroll
        for (int t = 0; t < 16; ++t)
            rv[t] = rr[repBase + (u0 + t) * repStride + repOff];
        #pragma unroll
        for (int j = 0; j < 8; ++j) {
            const float* w3r = W3 + (size_t)(h0 + j) * 112 + colbase + u0;
            float4 w0 = *reinterpret_cast<const float4*>(w3r);
            float4 w1 = *reinterpret_cast<const float4*>(w3r + 4);
            float4 w2 = *reinterpret_cast<const float4*>(w3r + 8);
            float4 w3v = *reinterpret_cast<const float4*>(w3r + 12);
            const float* wp0 = reinterpret_cast<const float*>(&w0);
            const float* wp1 = reinterpret_cast<const float*>(&w1);
            const float* wp2 = reinterpret_cast<const float*>(&w2);
            const float* wp3 = reinterpret_cast<const float*>(&w3v);
            float a = accj[j];
            #pragma unroll
            for (int c = 0; c < 4; ++c) a = fmaf(wp0[c], rv[c], a);
            #pragma unroll
            for (int c = 0; c < 4; ++c) a = fmaf(wp1[c], rv[4 + c], a);
            #pragma unroll
            for (int c = 0; c < 4; ++c) a = fmaf(wp2[c], rv[8 + c], a);
            #pragma unroll
            for (int c = 0; c < 4; ++c) a = fmaf(wp3[c], rv[12 + c], a);
            accj[j] = a;
        }
    }
    half8 o;
    #pragma unroll
    for (int j = 0; j < 8; ++j) o[j] = (_Float16)(accj[j] * nrm);
    *reinterpret_cast<half8*>(dst) = o;
}

// ---------------------------------------------------------------------------
// pair6: grid (16, 64): bg owns 4 b's; 4 blocks/CU (LDS ~38 KB).
// Startup: stage geom/rep; V -> fp16 B-frags in LDS (conflict-free b128).
// Main (4 passes x 1 b, low register pressure): layer1 in fp16 A-frag regs
//   (W1 global/L1) -> fp16 MFMA layer2 (W2 frags global/L1, acc[8]=32 VGPR)
//   -> ssp -> fp16 LDS transpose (stride 136) -> fp16 MFMA combine vs V frags
//   -> G-weight -> 16-lane shuffle reduce.
// Output: partial[z][bg][a]; counter-based finalize by last of 16 blocks.
// ---------------------------------------------------------------------------
__global__ __launch_bounds__(256, 4)
void pair6(const float* __restrict__ rep, const float* __restrict__ geom,
           const float* __restrict__ mask, const float* __restrict__ W1,
           const float* __restrict__ W3, const _Float16* __restrict__ w2f,
           float* __restrict__ partial, unsigned* __restrict__ counter,
           float* __restrict__ out) {
    const int bg = blockIdx.x;           // b in [4bg, 4bg+4)
    const int z  = blockIdx.y;
    const int tid = threadIdx.x;
    const int wv = tid >> 6, lane = tid & 63;
    const int m = lane & 15, quad = lane >> 4;

    __shared__ __align__(16) _Float16 sVf[8192];         // 16384 B [b4][kt][lane][j]
    __shared__ __align__(16) _Float16 sH2w[4][16 * 136]; // 17408 B (sRep alias)
    __shared__ float sPosA[192];
    __shared__ float sPosB[12];
    __shared__ __align__(16) float sYw[4][16][8];        // 2048 B (per-wave, per-pass)
    __shared__ unsigned sLastFlag;

    float* sRep = reinterpret_cast<float*>(&sH2w[0][0]); // 960 floats, dead later

    // ---- stage geom + rep ----
    if (tid < 192) sPosA[tid] = geom[z * 192 + tid];
    else if (tid < 204) sPosB[tid - 192] = geom[((size_t)z * 64 + bg * 4) * 3 + (tid - 192)];
    if (tid < 240)
        reinterpret_cast<float4*>(sRep)[tid] =
            reinterpret_cast<const float4*>(rep + ((size_t)z * 64 + bg * 4) * 240)[tid];
    __syncthreads();

    // ---- V compute: one fragment per slot, class per wave ----
    const float nI = INV_SQRT_H;
    if (wv == 0) {
        const int r = lane;
        const int b = r >> 4, kt = (r >> 2) & 3, qd = r & 3;
        vslot<64>(W3, sRep + b * 240, 0, 0, 1, 0, kt * 32 + qd * 8, NORM0 * nI,
                  sVf + (b * 4 + kt) * 512 + (qd * 16 + 0) * 8);
    } else if (wv == 1) {
        #pragma unroll
        for (int s = 0; s < 3; ++s) {
            const int idx = lane + 64 * s;
            const int mm = idx % 3, r = idx / 3;
            const int b = r >> 4, kt = (r >> 2) & 3, qd = r & 3;
            vslot<32>(W3, sRep + b * 240, 64, 64, 3, mm, kt * 32 + qd * 8, NORM1 * nI,
                      sVf + (b * 4 + kt) * 512 + (qd * 16 + 1 + mm) * 8);
        }
    } else if (wv == 2) {
        #pragma unroll
        for (int s = 0; s < 5; ++s) {
            const int idx = lane + 64 * s;
            const int t5 = idx % 5, r = idx / 5;
            const int b = r >> 4, kt = (r >> 2) & 3, qd = r & 3;
            vslot<16>(W3, sRep + b * 240, 96, 160, 5, t5, kt * 32 + qd * 8, NORM2 * nI,
                      sVf + (b * 4 + kt) * 512 + (qd * 16 + 4 + t5) * 8);
        }
    } else {
        half8 zz = {};
        #pragma unroll
        for (int s = 0; s < 7; ++s) {
            const int idx = lane + 64 * s;
            const int t7 = idx % 7, r = idx / 7;
            const int b = r >> 4, kt = (r >> 2) & 3, qd = r & 3;
            *reinterpret_cast<half8*>(sVf + (b * 4 + kt) * 512 + (qd * 16 + 9 + t7) * 8) = zz;
        }
    }
    __syncthreads();   // sVf ready; sRep dead -> sH2w usable

    // ---- main loop: 4 passes x 1 b (low register pressure) ----
    const int aLoc = wv * 16 + m;
    const float axw = sPosA[aLoc * 3 + 0];
    const float ayw = sPosA[aLoc * 3 + 1];
    const float azw = sPosA[aLoc * 3 + 2];
    _Float16* myH2 = &sH2w[wv][0];
    float outAcc[4] = {0.f, 0.f, 0.f, 0.f};

    for (int bl = 0; bl < 4; ++bl) {
        // pair geometry
        const float bx = sPosB[bl * 3 + 0];
        const float by = sPosB[bl * 3 + 1];
        const float bz = sPosB[bl * 3 + 2];
        const float dx = axw - bx, dy = ayw - by, dz = azw - bz;
        const float r2 = dx * dx + dy * dy + dz * dz;
        const float r = sqrtf(fmaxf(r2, 1e-12f));
        const float nzf = (r2 > 1e-10f) ? 1.0f : 0.0f;
        const float ir = 1.0f / r;
        const float x = dx * ir, y = dy * ir, zz = dz * ir;
        if (quad == 0) {
            float4 g0, g1;
            g0.x = S3 * x * nzf; g0.y = S3 * y * nzf; g0.z = S3 * zz * nzf;
            g0.w = S15 * x * y * nzf;
            g1.x = S15 * y * zz * nzf;
            g1.y = 0.5f * S5 * (3.0f * zz * zz - 1.0f) * nzf;
            g1.z = S15 * x * zz * nzf;
            g1.w = 0.5f * S15 * (x * x - y * y) * nzf;
            *reinterpret_cast<float4*>(&sYw[wv][m][0]) = g0;
            *reinterpret_cast<float4*>(&sYw[wv][m][4]) = g1;
        }
        const float u = r * INV_STEP;
        int i0 = (int)floorf(u);
        const float d0 = u - (float)i0;
        float c0 = (i0 >= 0 && i0 < NB_) ? __cosf(HALF_PI * d0) : 0.f;
        const int i1 = i0 + 1;
        const float d1 = d0 - 1.0f;
        float c1 = (i1 >= 0 && i1 < NB_ && d1 > -1.0f) ? __cosf(HALF_PI * d1) : 0.f;
        const int i0c = min(max(i0, 0), NB_ - 1);
        const int i1c = min(max(i1, 0), NB_ - 1);
        const float c0v = c0 * INV_SQRT_NB;
        const float c1v = c1 * INV_SQRT_NB;
        const float* w1r0 = W1 + i0c * H_;
        const float* w1r1 = W1 + i1c * H_;

        f32x4 acc[8];
        #pragma unroll
        for (int nt = 0; nt < 8; ++nt) {
            acc[nt][0] = 0.f; acc[nt][1] = 0.f; acc[nt][2] = 0.f; acc[nt][3] = 0.f;
        }

        // layer1 (fp16 A-frag regs, W1 via L1) + layer2 MFMA (W2 frags via L1)
        #pragma unroll
        for (int kt = 0; kt < 4; ++kt) {
            const int koff = kt * 32 + quad * 8;
            float4 wa0 = *reinterpret_cast<const float4*>(w1r0 + koff);
            float4 wa1 = *reinterpret_cast<const float4*>(w1r0 + koff + 4);
            float4 wb0 = *reinterpret_cast<const float4*>(w1r1 + koff);
            float4 wb1 = *reinterpret_cast<const float4*>(w1r1 + koff + 4);
            const float* a0p = reinterpret_cast<const float*>(&wa0);
            const float* a1p = reinterpret_cast<const float*>(&wa1);
            const float* b0p = reinterpret_cast<const float*>(&wb0);
            const float* b1p = reinterpret_cast<const float*>(&wb1);
            half8 ah;
            #pragma unroll
            for (int j = 0; j < 8; ++j) {
                float w0 = (j < 4) ? a0p[j] : a1p[j - 4];
                float w1v = (j < 4) ? b0p[j] : b1p[j - 4];
                ah[j] = (_Float16)ssp_f(fmaf(c0v, w0, c1v * w1v));
            }
            const _Float16* bhp = w2f + (size_t)(kt * 8) * 512 + (size_t)lane * 8;
            #pragma unroll
            for (int nt = 0; nt < 8; ++nt) {
                half8 bh = *reinterpret_cast<const half8*>(bhp + nt * 512);
                acc[nt] = __builtin_amdgcn_mfma_f32_16x16x32_f16(ah, bh, acc[nt], 0, 0, 0);
            }
        }

        // epilogue: ssp -> fp16 LDS transpose (stride 136) -> combine MFMA
        #pragma unroll
        for (int nt = 0; nt < 8; ++nt)
            #pragma unroll
            for (int reg = 0; reg < 4; ++reg)
                myH2[(quad * 4 + reg) * 136 + nt * 16 + m] =
                    (_Float16)ssp_f(acc[nt][reg] * INV_SQRT_H);

        f32x4 T0 = {0.f, 0.f, 0.f, 0.f};
        f32x4 T1 = {0.f, 0.f, 0.f, 0.f};
        #pragma unroll
        for (int kt = 0; kt < 4; ++kt) {
            half8 ah2 = *reinterpret_cast<const half8*>(&myH2[m * 136 + kt * 32 + quad * 8]);
            half8 bv = *reinterpret_cast<const half8*>(&sVf[(bl * 4 + kt) * 512 + lane * 8]);
            if (kt & 1) T1 = __builtin_amdgcn_mfma_f32_16x16x32_f16(ah2, bv, T1, 0, 0, 0);
            else        T0 = __builtin_amdgcn_mfma_f32_16x16x32_f16(ah2, bv, T0, 0, 0, 0);
        }

        // G-weight (T C-layout: col=lane&15=cm, row=quad*4+reg) + 16-lane reduce
        const int comp = (m >= 1 && m <= 8) ? (m - 1) : 0;
        float ps[4];
        #pragma unroll
        for (int reg = 0; reg < 4; ++reg) {
            const int row = quad * 4 + reg;
            const float Tv = T0[reg] + T1[reg];
            const float yv = sYw[wv][row][comp];
            const float g = (m == 0) ? 1.0f : ((m <= 8) ? yv : 0.0f);
            ps[reg] = Tv * g;
        }
        #pragma unroll
        for (int off = 1; off < 16; off <<= 1)
            #pragma unroll
            for (int reg = 0; reg < 4; ++reg)
                ps[reg] += __shfl_xor(ps[reg], off);
        #pragma unroll
        for (int reg = 0; reg < 4; ++reg) outAcc[reg] += ps[reg];
    }

    // ---- write partials (agent scope) + completion-counter finalize ----
    if (m == 0) {
        float* pb = partial + ((size_t)(z * 16 + bg)) * 64 + wv * 16 + quad * 4;
        #pragma unroll
        for (int reg = 0; reg < 4; ++reg)
            __hip_atomic_store(&pb[reg], outAcc[reg], __ATOMIC_RELAXED,
                               __HIP_MEMORY_SCOPE_AGENT);
    }
    __threadfence();
    __syncthreads();
    if (tid == 0) {
        unsigned old = atomicAdd(&counter[z], 1u);
        sLastFlag = (old == 0xAAAAAAAAu + 15u) ? 1u : 0u;
    }
    __syncthreads();
    if (sLastFlag) {
        __threadfence();
        if (tid < 64) {
            const float mk = mask[z * 64 + tid];
            float s = mk;
            #pragma unroll
            for (int off = 32; off > 0; off >>= 1) s += __shfl_xor(s, off);
            const float inv = rsqrtf(s);
            float acc = 0.f;
            #pragma unroll
            for (int b2 = 0; b2 < 16; ++b2)
                acc += __hip_atomic_load(&partial[((size_t)(z * 16 + b2)) * 64 + tid],
                                         __ATOMIC_RELAXED, __HIP_MEMORY_SCOPE_AGENT);
            out[z * 64 + tid] = sp_f(acc * inv) * mk;
        }
    }
}

extern "C" void kernel_launch(void* const* d_in, const int* in_sizes, int n_in,
                              void* d_out, int out_size, void* d_ws, size_t ws_size,
                              hipStream_t stream) {
    const float* rep  = (const float*)d_in[0];
    const float* geom = (const float*)d_in[1];
    const float* mask = (const float*)d_in[2];
    const float* W1   = (const float*)d_in[3];
    const float* W2   = (const float*)d_in[4];
    const float* W3   = (const float*)d_in[5];
    float* out = (float*)d_out;

    _Float16* w2f = (_Float16*)d_ws;                          // 32768 B
    float* partial = (float*)((char*)d_ws + 32768);           // 64*16*64*4 = 262144 B
    unsigned* counter = (unsigned*)((char*)d_ws + 32768 + 262144);  // 64 uints (0xAA)

    w2half<<<16, 256, 0, stream>>>(W2, w2f);
    pair6<<<dim3(16, 64), 256, 0, stream>>>(rep, geom, mask, W1, W3, w2f,
                                            partial, counter, out);
}

// Round 11
// 264.182 us; speedup vs baseline: 1.2516x; 1.1223x over previous
//
#include <hip/hip_runtime.h>
#include <math.h>

// B=64, A=64, MULS=((64,0),(32,1),(16,2)) -> DIM_IN=240, NB=32, H=128, MOUT=112
#define H_ 128
#define NB_ 32

#define INV_STEP 3.1f
#define HALF_PI 1.57079632679489662f
#define INV_SQRT_NB 0.17677669529663689f
#define INV_SQRT_H 0.08838834764831845f
#define NORM0 0.125f
#define NORM1 0.10206207261596575f
#define NORM2 0.11180339887498948f
#define S3 1.7320508075688772f
#define S5 2.23606797749979f
#define S15 3.872983346207417f
// log2-domain softplus constants
#define SSP_C1 7.2134752044448170f    // 5*log2(e)
#define SSP_C2 0.1386294361119891f    // ln2/5

typedef __attribute__((ext_vector_type(8))) _Float16 half8;
typedef __attribute__((ext_vector_type(4))) float f32x4;

// v_exp_f32 computes 2^x; v_log_f32 computes log2(x)
__device__ __forceinline__ float ssp_f(float x) {
    float u = SSP_C1 * x;
    float p = __builtin_amdgcn_exp2f(-fabsf(u));
    float t = fmaxf(u, 0.f) + __builtin_amdgcn_logf(1.f + p);
    return fmaf(t, SSP_C2, -SSP_C2);
}
__device__ __forceinline__ float sp_f(float x) {
    float u = SSP_C1 * x;
    float p = __builtin_amdgcn_exp2f(-fabsf(u));
    float t = fmaxf(u, 0.f) + __builtin_amdgcn_logf(1.f + p);
    return t * SSP_C2;
}

// ---------------------------------------------------------------------------
// prep: W2 (fp32) -> fp16 MFMA-B-fragment order; W1 (fp32) -> fp16 row-major.
// Grid 16 x 256. Block 0 additionally converts W1.
// ---------------------------------------------------------------------------
__global__ void prep(const float* __restrict__ W2, const float* __restrict__ W1,
                     _Float16* __restrict__ w2f, _Float16* __restrict__ w1h) {
    const int e0 = (blockIdx.x * 256 + threadIdx.x) * 4;
    #pragma unroll
    for (int t = 0; t < 4; ++t) {
        const int pos = e0 + t;
        const int j = pos & 7, lane = (pos >> 3) & 63, fn = pos >> 9;
        const int kt = fn >> 3, nt = fn & 7;
        const int k = kt * 32 + (lane >> 4) * 8 + j;
        const int n = nt * 16 + (lane & 15);
        w2f[pos] = (_Float16)W2[k * 128 + n];
    }
    if (blockIdx.x == 0) {
        #pragma unroll
        for (int t = 0; t < 16; ++t) {
            const int idx = threadIdx.x + t * 256;   // 4096 elements
            w1h[idx] = (_Float16)W1[idx];
        }
    }
}

// V-slot helper: computes one fp16 B-fragment (8 h values for one (b,kt,qd,cm))
template <int K>
__device__ __forceinline__ void vslot(const float* __restrict__ W3,
                                      const float* __restrict__ rr,
                                      int colbase, int repBase, int repStride,
                                      int repOff, int h0, float nrm,
                                      _Float16* __restrict__ dst) {
    float accj[8] = {0.f, 0.f, 0.f, 0.f, 0.f, 0.f, 0.f, 0.f};
    for (int u0 = 0; u0 < K; u0 += 16) {
        float rv[16];
        #pragma unroll
        for (int t = 0; t < 16; ++t)
            rv[t] = rr[repBase + (u0 + t) * repStride + repOff];
        #pragma unroll
        for (int j = 0; j < 8; ++j) {
            const float* w3r = W3 + (size_t)(h0 + j) * 112 + colbase + u0;
            float4 w0 = *reinterpret_cast<const float4*>(w3r);
            float4 w1 = *reinterpret_cast<const float4*>(w3r + 4);
            float4 w2 = *reinterpret_cast<const float4*>(w3r + 8);
            float4 w3v = *reinterpret_cast<const float4*>(w3r + 12);
            const float* wp0 = reinterpret_cast<const float*>(&w0);
            const float* wp1 = reinterpret_cast<const float*>(&w1);
            const float* wp2 = reinterpret_cast<const float*>(&w2);
            const float* wp3 = reinterpret_cast<const float*>(&w3v);
            float a = accj[j];
            #pragma unroll
            for (int c = 0; c < 4; ++c) a = fmaf(wp0[c], rv[c], a);
            #pragma unroll
            for (int c = 0; c < 4; ++c) a = fmaf(wp1[c], rv[4 + c], a);
            #pragma unroll
            for (int c = 0; c < 4; ++c) a = fmaf(wp2[c], rv[8 + c], a);
            #pragma unroll
            for (int c = 0; c < 4; ++c) a = fmaf(wp3[c], rv[12 + c], a);
            accj[j] = a;
        }
    }
    half8 o;
    #pragma unroll
    for (int j = 0; j < 8; ++j) o[j] = (_Float16)(accj[j] * nrm);
    *reinterpret_cast<half8*>(dst) = o;
}

// ---------------------------------------------------------------------------
// pair7: grid (16, 64): bg owns 4 b's; 3 blocks/CU (VGPR-bound, no spill).
// Startup: stage geom/rep; V -> fp16 B-frags in LDS (conflict-free b128).
// Main (4 passes x 1 b): layer1 in fp16 A-frag regs (fp16 W1 via L1) ->
//   fp16 MFMA layer2 (W2 frags via L1) -> ssp -> fp16 LDS transpose
//   (stride 136) -> fp16 MFMA combine vs V frags -> G-weight -> 16-lane
//   shuffle reduce.
// Output: partial[z][bg][a]; counter-based finalize by last of 16 blocks.
// ---------------------------------------------------------------------------
__global__ __launch_bounds__(256, 3)
void pair7(const float* __restrict__ rep, const float* __restrict__ geom,
           const float* __restrict__ mask, const _Float16* __restrict__ w1h,
           const float* __restrict__ W3, const _Float16* __restrict__ w2f,
           float* __restrict__ partial, unsigned* __restrict__ counter,
           float* __restrict__ out) {
    const int bg = blockIdx.x;           // b in [4bg, 4bg+4)
    const int z  = blockIdx.y;
    const int tid = threadIdx.x;
    const int wv = tid >> 6, lane = tid & 63;
    const int m = lane & 15, quad = lane >> 4;

    __shared__ __align__(16) _Float16 sVf[8192];         // 16384 B [b4][kt][lane][j]
    __shared__ __align__(16) _Float16 sH2w[4][16 * 136]; // 17408 B (sRep alias)
    __shared__ float sPosA[192];
    __shared__ float sPosB[12];
    __shared__ __align__(16) float sYw[4][16][8];        // 2048 B
    __shared__ unsigned sLastFlag;

    float* sRep = reinterpret_cast<float*>(&sH2w[0][0]); // 960 floats, dead later

    // ---- stage geom + rep ----
    if (tid < 192) sPosA[tid] = geom[z * 192 + tid];
    else if (tid < 204) sPosB[tid - 192] = geom[((size_t)z * 64 + bg * 4) * 3 + (tid - 192)];
    if (tid < 240)
        reinterpret_cast<float4*>(sRep)[tid] =
            reinterpret_cast<const float4*>(rep + ((size_t)z * 64 + bg * 4) * 240)[tid];
    __syncthreads();

    // ---- V compute: one fragment per slot, class per wave ----
    const float nI = INV_SQRT_H;
    if (wv == 0) {
        const int r = lane;
        const int b = r >> 4, kt = (r >> 2) & 3, qd = r & 3;
        vslot<64>(W3, sRep + b * 240, 0, 0, 1, 0, kt * 32 + qd * 8, NORM0 * nI,
                  sVf + (b * 4 + kt) * 512 + (qd * 16 + 0) * 8);
    } else if (wv == 1) {
        #pragma unroll
        for (int s = 0; s < 3; ++s) {
            const int idx = lane + 64 * s;
            const int mm = idx % 3, r = idx / 3;
            const int b = r >> 4, kt = (r >> 2) & 3, qd = r & 3;
            vslot<32>(W3, sRep + b * 240, 64, 64, 3, mm, kt * 32 + qd * 8, NORM1 * nI,
                      sVf + (b * 4 + kt) * 512 + (qd * 16 + 1 + mm) * 8);
        }
    } else if (wv == 2) {
        #pragma unroll
        for (int s = 0; s < 5; ++s) {
            const int idx = lane + 64 * s;
            const int t5 = idx % 5, r = idx / 5;
            const int b = r >> 4, kt = (r >> 2) & 3, qd = r & 3;
            vslot<16>(W3, sRep + b * 240, 96, 160, 5, t5, kt * 32 + qd * 8, NORM2 * nI,
                      sVf + (b * 4 + kt) * 512 + (qd * 16 + 4 + t5) * 8);
        }
    } else {
        half8 zz = {};
        #pragma unroll
        for (int s = 0; s < 7; ++s) {
            const int idx = lane + 64 * s;
            const int t7 = idx % 7, r = idx / 7;
            const int b = r >> 4, kt = (r >> 2) & 3, qd = r & 3;
            *reinterpret_cast<half8*>(sVf + (b * 4 + kt) * 512 + (qd * 16 + 9 + t7) * 8) = zz;
        }
    }
    __syncthreads();   // sVf ready; sRep dead -> sH2w usable

    // ---- main loop: 4 passes x 1 b ----
    const int aLoc = wv * 16 + m;
    const float axw = sPosA[aLoc * 3 + 0];
    const float ayw = sPosA[aLoc * 3 + 1];
    const float azw = sPosA[aLoc * 3 + 2];
    _Float16* myH2 = &sH2w[wv][0];
    float outAcc[4] = {0.f, 0.f, 0.f, 0.f};

    for (int bl = 0; bl < 4; ++bl) {
        // pair geometry
        const float bx = sPosB[bl * 3 + 0];
        const float by = sPosB[bl * 3 + 1];
        const float bz = sPosB[bl * 3 + 2];
        const float dx = axw - bx, dy = ayw - by, dz = azw - bz;
        const float r2 = dx * dx + dy * dy + dz * dz;
        const float r = sqrtf(fmaxf(r2, 1e-12f));
        const float nzf = (r2 > 1e-10f) ? 1.0f : 0.0f;
        const float ir = 1.0f / r;
        const float x = dx * ir, y = dy * ir, zz = dz * ir;
        if (quad == 0) {
            float4 g0, g1;
            g0.x = S3 * x * nzf; g0.y = S3 * y * nzf; g0.z = S3 * zz * nzf;
            g0.w = S15 * x * y * nzf;
            g1.x = S15 * y * zz * nzf;
            g1.y = 0.5f * S5 * (3.0f * zz * zz - 1.0f) * nzf;
            g1.z = S15 * x * zz * nzf;
            g1.w = 0.5f * S15 * (x * x - y * y) * nzf;
            *reinterpret_cast<float4*>(&sYw[wv][m][0]) = g0;
            *reinterpret_cast<float4*>(&sYw[wv][m][4]) = g1;
        }
        const float u = r * INV_STEP;
        int i0 = (int)floorf(u);
        const float d0 = u - (float)i0;
        float c0 = (i0 >= 0 && i0 < NB_) ? __cosf(HALF_PI * d0) : 0.f;
        const int i1 = i0 + 1;
        const float d1 = d0 - 1.0f;
        float c1 = (i1 >= 0 && i1 < NB_ && d1 > -1.0f) ? __cosf(HALF_PI * d1) : 0.f;
        const int i0c = min(max(i0, 0), NB_ - 1);
        const int i1c = min(max(i1, 0), NB_ - 1);
        const float c0v = c0 * INV_SQRT_NB;
        const float c1v = c1 * INV_SQRT_NB;
        const _Float16* w1r0 = w1h + i0c * H_;
        const _Float16* w1r1 = w1h + i1c * H_;

        f32x4 acc[8];
        #pragma unroll
        for (int nt = 0; nt < 8; ++nt) {
            acc[nt][0] = 0.f; acc[nt][1] = 0.f; acc[nt][2] = 0.f; acc[nt][3] = 0.f;
        }

        // layer1 (fp16 A-frag regs, fp16 W1 via L1) + layer2 MFMA (W2 frags via L1)
        #pragma unroll
        for (int kt = 0; kt < 4; ++kt) {
            const int koff = kt * 32 + quad * 8;
            half8 h0 = *reinterpret_cast<const half8*>(w1r0 + koff);
            half8 h1 = *reinterpret_cast<const half8*>(w1r1 + koff);
            half8 ah;
            #pragma unroll
            for (int j = 0; j < 8; ++j)
                ah[j] = (_Float16)ssp_f(fmaf(c0v, (float)h0[j], c1v * (float)h1[j]));
            const _Float16* bhp = w2f + (size_t)(kt * 8) * 512 + (size_t)lane * 8;
            #pragma unroll
            for (int nt = 0; nt < 8; ++nt) {
                half8 bh = *reinterpret_cast<const half8*>(bhp + nt * 512);
                acc[nt] = __builtin_amdgcn_mfma_f32_16x16x32_f16(ah, bh, acc[nt], 0, 0, 0);
            }
        }

        // epilogue: ssp -> fp16 LDS transpose (stride 136) -> combine MFMA
        #pragma unroll
        for (int nt = 0; nt < 8; ++nt)
            #pragma unroll
            for (int reg = 0; reg < 4; ++reg)
                myH2[(quad * 4 + reg) * 136 + nt * 16 + m] =
                    (_Float16)ssp_f(acc[nt][reg] * INV_SQRT_H);

        f32x4 T0 = {0.f, 0.f, 0.f, 0.f};
        f32x4 T1 = {0.f, 0.f, 0.f, 0.f};
        #pragma unroll
        for (int kt = 0; kt < 4; ++kt) {
            half8 ah2 = *reinterpret_cast<const half8*>(&myH2[m * 136 + kt * 32 + quad * 8]);
            half8 bv = *reinterpret_cast<const half8*>(&sVf[(bl * 4 + kt) * 512 + lane * 8]);
            if (kt & 1) T1 = __builtin_amdgcn_mfma_f32_16x16x32_f16(ah2, bv, T1, 0, 0, 0);
            else        T0 = __builtin_amdgcn_mfma_f32_16x16x32_f16(ah2, bv, T0, 0, 0, 0);
        }

        // G-weight (T C-layout: col=lane&15=cm, row=quad*4+reg) + 16-lane reduce
        const int comp = (m >= 1 && m <= 8) ? (m - 1) : 0;
        float ps[4];
        #pragma unroll
        for (int reg = 0; reg < 4; ++reg) {
            const int row = quad * 4 + reg;
            const float Tv = T0[reg] + T1[reg];
            const float yv = sYw[wv][row][comp];
            const float g = (m == 0) ? 1.0f : ((m <= 8) ? yv : 0.0f);
            ps[reg] = Tv * g;
        }
        #pragma unroll
        for (int off = 1; off < 16; off <<= 1)
            #pragma unroll
            for (int reg = 0; reg < 4; ++reg)
                ps[reg] += __shfl_xor(ps[reg], off);
        #pragma unroll
        for (int reg = 0; reg < 4; ++reg) outAcc[reg] += ps[reg];
    }

    // ---- write partials (agent scope) + completion-counter finalize ----
    if (m == 0) {
        float* pb = partial + ((size_t)(z * 16 + bg)) * 64 + wv * 16 + quad * 4;
        #pragma unroll
        for (int reg = 0; reg < 4; ++reg)
            __hip_atomic_store(&pb[reg], outAcc[reg], __ATOMIC_RELAXED,
                               __HIP_MEMORY_SCOPE_AGENT);
    }
    __threadfence();
    __syncthreads();
    if (tid == 0) {
        unsigned old = atomicAdd(&counter[z], 1u);
        sLastFlag = (old == 0xAAAAAAAAu + 15u) ? 1u : 0u;
    }
    __syncthreads();
    if (sLastFlag) {
        __threadfence();
        if (tid < 64) {
            const float mk = mask[z * 64 + tid];
            float s = mk;
            #pragma unroll
            for (int off = 32; off > 0; off >>= 1) s += __shfl_xor(s, off);
            const float inv = rsqrtf(s);
            float acc = 0.f;
            #pragma unroll
            for (int b2 = 0; b2 < 16; ++b2)
                acc += __hip_atomic_load(&partial[((size_t)(z * 16 + b2)) * 64 + tid],
                                         __ATOMIC_RELAXED, __HIP_MEMORY_SCOPE_AGENT);
            out[z * 64 + tid] = sp_f(acc * inv) * mk;
        }
    }
}

extern "C" void kernel_launch(void* const* d_in, const int* in_sizes, int n_in,
                              void* d_out, int out_size, void* d_ws, size_t ws_size,
                              hipStream_t stream) {
    const float* rep  = (const float*)d_in[0];
    const float* geom = (const float*)d_in[1];
    const float* mask = (const float*)d_in[2];
    const float* W1   = (const float*)d_in[3];
    const float* W2   = (const float*)d_in[4];
    const float* W3   = (const float*)d_in[5];
    float* out = (float*)d_out;

    _Float16* w2f = (_Float16*)d_ws;                          // 32768 B
    _Float16* w1h = (_Float16*)((char*)d_ws + 32768);         // 8192 B
    float* partial = (float*)((char*)d_ws + 40960);           // 262144 B
    unsigned* counter = (unsigned*)((char*)d_ws + 40960 + 262144);  // 64 uints (0xAA)

    prep<<<16, 256, 0, stream>>>(W2, W1, w2f, w1h);
    pair7<<<dim3(16, 64), 256, 0, stream>>>(rep, geom, mask, w1h, W3, w2f,
                                            partial, counter, out);
}